// Round 9
// baseline (3925.036 us; speedup 1.0000x reference)
//
#include <hip/hip_runtime.h>
#include <hip/hip_bf16.h>

// ---------------------------------------------------------------------------
// BiLSTM-CRF on MI355X, round 13.
//  r12 post-mortem: store-drain restored r5 parity (1822 vs 1790) — k3's
//  ~3.5us/step is the store->visibility->detect round trip, converged at this
//  topology. Remaining 866us is mostly k2 (~300-350us: 137 GFLOP + 268MB xq
//  write + 268MB read).
//  Round-13: FUSE k2 INTO k3 — x-projection (x_t @ W_ih^T) is independent of
//  the recurrence, so compute it per-step in k3 DURING the poll wait:
//   - issue poll round 0 FIRST, then 32 x-proj MFMAs (W_ih A-frags pre-built
//     by k0 -> coalesced 1KB/frag loads; x B-frags from L2-resident emb_bf),
//     then sentinel check: round-0 latency hides under real work.
//   - h-MFMAs accumulate on top of the same accumulators; bias added in the
//     register epilogue (no xq bf16 intermediate rounding anymore).
//   - k2, xq (268MB x2 traffic) deleted. k0 now emits frag-order W_ih.
//  Kept: r12 store+vmcnt(0) drain; r11 lane-local gates (cell-pair row perm,
//  zero cross-lane epilogue); r5 sentinel poll shape (batched atomic loads,
//  ONE __all gate); r4 frag-order H (k4 unchanged).
// ---------------------------------------------------------------------------

typedef short short8  __attribute__((ext_vector_type(8)));
typedef short short4v __attribute__((ext_vector_type(4)));
typedef float floatx4 __attribute__((ext_vector_type(4)));

#define OFF_XQ    0ULL               // (unused since r13; kept for offset stability)
#define OFF_H     268435456ULL       // [2][512] frag-order blocks 64KB   67,108,864 B
#define OFF_EMB   335544320ULL       // [32768][512] bf16                 33,554,432 B
#define OFF_WIH   369098752ULL       // [2][1048576] frag-order W_ih bf16  4,194,304 B
#define OFF_FCW   373293056ULL       // [48][1024] bf16                       98,304 B
#define OFF_BIAS  373391360ULL       // [2][2048] f32                         16,384 B
#define OFF_EM    373538816ULL       // [32768][48] f32                    6,291,456 B
#define OFF_NUM   379830272ULL       // [64] f32
#define OFF_LOGZ  379830528ULL       // [64] f32
#define WS_NEED   379830784ULL

__device__ __forceinline__ unsigned short f2bf(float f) {
  __hip_bfloat16 h = __float2bfloat16(f);
  unsigned short u; __builtin_memcpy(&u, &h, 2); return u;
}
__device__ __forceinline__ float bf2f(unsigned short u) {
  __hip_bfloat16 h; __builtin_memcpy(&h, &u, 2); return __bfloat162float(h);
}
__device__ __forceinline__ float sigm(float x) { return 1.0f / (1.0f + __expf(-x)); }
__device__ __forceinline__ float tanh_f(float x) {
  x = fmaxf(fminf(x, 15.0f), -15.0f);
  float e = __expf(2.0f * x);
  return (e - 1.0f) / (e + 1.0f);
}
// bijective time->block scramble (keeps H-slot addresses spread)
__device__ __forceinline__ int permt(int t) { return (t * 167) & 511; }

// ---------------- k_init: fill Hall with sentinel 0xFFFFFFFF ----------------
__global__ void k_init(uint4* __restrict__ H) {
  size_t i = (size_t)blockIdx.x * 256 + threadIdx.x;   // 16384*256 uint4 = 64 MB
  H[i] = (uint4){0xFFFFFFFFu, 0xFFFFFFFFu, 0xFFFFFFFFu, 0xFFFFFFFFu};
}

// ---------------- k0: conversions + frag-order W_ih ----------------
// wfrag linear j (per dir) = ((g*16+ks)*2+T)*512 + l*8 + e :
//   lane l of block g reads 16B at +((g*16+ks)*2+T)*1024B + l*16B (coalesced 1KB/frag)
//   source row = gate*512 + g*8 + 2*cA + T (nl=l&15, cA=nl>>2, gate=nl&3),
//   col = ks*32 + (l>>4)*8 + e  — identical per-lane gather as k3's Bf_hh.
__global__ void k0_conv(const float* __restrict__ wf, const float* __restrict__ wb,
                        const float* __restrict__ fcw,
                        const float* __restrict__ bihf, const float* __restrict__ bhhf,
                        const float* __restrict__ bihb, const float* __restrict__ bhhb,
                        unsigned short* __restrict__ wfrag,
                        unsigned short* __restrict__ fcw_bf,
                        float* __restrict__ bias) {
  int i = blockIdx.x * 256 + threadIdx.x;
  if (i < 2097152) {
    int d = i >> 20;
    int j = i & 1048575;
    const float* w = d ? wb : wf;
    int e = j & 7, l = (j >> 3) & 63;
    int T = (j >> 9) & 1, ks = (j >> 10) & 15, g = j >> 14;
    int nl = l & 15;
    int row = (nl & 3) * 512 + g * 8 + 2 * (nl >> 2) + T;
    int col = ks * 32 + (l >> 4) * 8 + e;
    wfrag[i] = f2bf(w[(size_t)row * 512 + col]);
    return;
  }
  int j = i - 2097152;
  if (j < 49152) { fcw_bf[j] = f2bf(fcw[j]); return; }
  j -= 49152;
  if (j < 2048) { bias[j] = bihf[j] + bhhf[j]; return; }
  j -= 2048;
  if (j < 2048) { bias[2048 + j] = bihb[j] + bhhb[j]; return; }
}

// ---------------- k1: embedding gather -> bf16 ----------------
__global__ void k1_embed(const float* __restrict__ tab, const int* __restrict__ x,
                         unsigned short* __restrict__ emb_bf) {
  int tid = threadIdx.x;
#pragma unroll
  for (int r = 0; r < 4; ++r) {
    int m = blockIdx.x * 4 + r;          // m = t*64 + b
    int b = m & 63, t = m >> 6;
    int tok = x[b * 512 + t];
    const float2* src = (const float2*)(tab + (size_t)tok * 512);
    float2 v = src[tid];
    unsigned int pk = (unsigned int)f2bf(v.x) | ((unsigned int)f2bf(v.y) << 16);
    ((unsigned int*)(emb_bf + (size_t)m * 512))[tid] = pk;
  }
}

// ---------------- k3: persistent BiLSTM, fused x-projection ----------------
__global__ __launch_bounds__(256, 1) void k3_lstm(
    const float* __restrict__ whh_f, const float* __restrict__ whh_b,
    const unsigned short* __restrict__ wfrag, const unsigned short* __restrict__ emb_bf,
    const float* __restrict__ bias, unsigned short* __restrict__ Hall) {
  const int wgid = blockIdx.x;
  const int d = wgid >> 6, g = wgid & 63;
  const int tid = threadIdx.x, l = tid & 63, wv = tid >> 6;
  const float* whh = d ? whh_b : whh_f;

  // W_hh as MFMA A-operand fragments with cell-pair row permutation:
  // frag row nl = cA*4 + gate; tile T=0 -> cell 2cA, T=1 -> cell 2cA+1.
  short8 Bf[32];
#pragma unroll
  for (int ks = 0; ks < 16; ++ks) {
#pragma unroll
    for (int T = 0; T < 2; ++T) {
      int nl = l & 15;
      int cA = nl >> 2, gate = nl & 3;
      int row = gate * 512 + g * 8 + 2 * cA + T;
      int k0 = ks * 32 + (l >> 4) * 8;
      const float* src = whh + (size_t)row * 512 + k0;
      short8 v;
#pragma unroll
      for (int j = 0; j < 8; ++j) v[j] = (short)f2bf(src[j]);
      Bf[ks * 2 + T] = v;
    }
  }

  const int q  = l >> 4;            // lane quarter: owns cells 2q, 2q+1
  const int bl = l & 15;            // batch low bits
  float cst[2] = {0.f, 0.f};

  // per-lane bias: bs[T][gate] for cells 2q+T
  float bs[2][4];
#pragma unroll
  for (int T = 0; T < 2; ++T)
#pragma unroll
    for (int r = 0; r < 4; ++r)
      bs[T][r] = bias[d * 2048 + r * 512 + g * 8 + 2 * q + T];

  const unsigned long long* Hb =
      (const unsigned long long*)((const unsigned int*)Hall + (size_t)d * 8388608);
  unsigned int* Hw = (unsigned int*)Hall + (size_t)d * 8388608;
  // frag-order W_ih for this block: lane l reads 16B at +frag*1024B + l*16B
  const unsigned short* wfd = wfrag + (size_t)d * 1048576 + (size_t)g * 16384 + l * 8;

  // producer dword slot within a (d,t) 16384-dword frag block:
  // dw = wv*4096 + (g>>2)*256 + (g&3)*64 + bl*4 + q  (wave = 256B contiguous)
  const size_t st_dw = (size_t)wv * 4096 + (size_t)(g >> 2) * 256
                     + (size_t)(g & 3) * 64 + bl * 4 + q;

  for (int s = 0; s < 512; ++s) {
    const int t = d ? (511 - s) : s;
    const int tp = d ? (t + 1) : (t - 1);
    const unsigned long long* Hu = Hb + (size_t)permt(tp) * 8192 + (size_t)wv * 2048;

    // ---- poll round 0: issue FIRST so its latency hides under x-proj ----
    unsigned long long u[32];
    if (s > 0) {
#pragma unroll
      for (int ks = 0; ks < 16; ++ks) {
        u[2 * ks]     = __hip_atomic_load(Hu + (size_t)ks * 128 + 2 * l,
                                          __ATOMIC_RELAXED, __HIP_MEMORY_SCOPE_AGENT);
        u[2 * ks + 1] = __hip_atomic_load(Hu + (size_t)ks * 128 + 2 * l + 1,
                                          __ATOMIC_RELAXED, __HIP_MEMORY_SCOPE_AGENT);
      }
    }
    __builtin_amdgcn_sched_barrier(0);   // pin poll issue before x-proj

    // ---- x-projection (independent of recurrence): 32 MFMAs, 4 chains ----
    // B-frag of x: lane (q,bl) holds emb[t*64 + wv*16 + bl][ks*32 + q*8 .. +8)
    const unsigned short* xbase = emb_bf + ((size_t)(t * 64 + wv * 16 + bl)) * 512 + q * 8;
    floatx4 acc0  = (floatx4){0.f, 0.f, 0.f, 0.f};   // cell 2q,   gates i,f,g,o
    floatx4 acc1  = (floatx4){0.f, 0.f, 0.f, 0.f};   // cell 2q+1
    floatx4 acc0b = (floatx4){0.f, 0.f, 0.f, 0.f};
    floatx4 acc1b = (floatx4){0.f, 0.f, 0.f, 0.f};
#pragma unroll
    for (int ks = 0; ks < 8; ++ks) {
      short8 x0 = *(const short8*)(xbase + ks * 32);
      short8 x1 = *(const short8*)(xbase + (ks + 8) * 32);
      short8 w0  = *(const short8*)(wfd + (size_t)(ks * 2 + 0) * 512);
      short8 w1  = *(const short8*)(wfd + (size_t)(ks * 2 + 1) * 512);
      short8 w0b = *(const short8*)(wfd + (size_t)((ks + 8) * 2 + 0) * 512);
      short8 w1b = *(const short8*)(wfd + (size_t)((ks + 8) * 2 + 1) * 512);
      acc0  = __builtin_amdgcn_mfma_f32_16x16x32_bf16(w0,  x0, acc0,  0, 0, 0);
      acc1  = __builtin_amdgcn_mfma_f32_16x16x32_bf16(w1,  x0, acc1,  0, 0, 0);
      acc0b = __builtin_amdgcn_mfma_f32_16x16x32_bf16(w0b, x1, acc0b, 0, 0, 0);
      acc1b = __builtin_amdgcn_mfma_f32_16x16x32_bf16(w1b, x1, acc1b, 0, 0, 0);
    }

    if (s > 0) {
      // ---- sentinel check on round 0; retry rounds r5-verbatim ----
      for (;;) {
        bool ok = true;
#pragma unroll
        for (int i = 0; i < 32; ++i) {
          ok &= ((unsigned int)u[i] != 0xFFFFFFFFu);
          ok &= ((unsigned int)(u[i] >> 32) != 0xFFFFFFFFu);
        }
        if (__all((int)ok)) break;
        __builtin_amdgcn_s_sleep(1);
#pragma unroll
        for (int ks = 0; ks < 16; ++ks) {
          u[2 * ks]     = __hip_atomic_load(Hu + (size_t)ks * 128 + 2 * l,
                                            __ATOMIC_RELAXED, __HIP_MEMORY_SCOPE_AGENT);
          u[2 * ks + 1] = __hip_atomic_load(Hu + (size_t)ks * 128 + 2 * l + 1,
                                            __ATOMIC_RELAXED, __HIP_MEMORY_SCOPE_AGENT);
        }
      }
      // ---- h-MFMAs accumulate on top: 4 chains of 8 ----
#pragma unroll
      for (int ks = 0; ks < 8; ++ks) {
        short8 af0, af1;
        __builtin_memcpy(&af0, &u[2 * ks], 8);
        __builtin_memcpy((char*)&af0 + 8, &u[2 * ks + 1], 8);
        __builtin_memcpy(&af1, &u[2 * (ks + 8)], 8);
        __builtin_memcpy((char*)&af1 + 8, &u[2 * (ks + 8) + 1], 8);
        acc0  = __builtin_amdgcn_mfma_f32_16x16x32_bf16(Bf[ks * 2 + 0], af0, acc0, 0, 0, 0);
        acc1  = __builtin_amdgcn_mfma_f32_16x16x32_bf16(Bf[ks * 2 + 1], af0, acc1, 0, 0, 0);
        acc0b = __builtin_amdgcn_mfma_f32_16x16x32_bf16(Bf[(ks + 8) * 2 + 0], af1, acc0b, 0, 0, 0);
        acc1b = __builtin_amdgcn_mfma_f32_16x16x32_bf16(Bf[(ks + 8) * 2 + 1], af1, acc1b, 0, 0, 0);
      }
    }
    acc0 += acc0b;
    acc1 += acc1b;

    // ---- elementwise: all 4 gates of both cells live in THIS lane ----
    float h2[2];
#pragma unroll
    for (int T = 0; T < 2; ++T) {
      floatx4 a = T ? acc1 : acc0;
      float gi = a[0] + bs[T][0];
      float gf = a[1] + bs[T][1];
      float gg = a[2] + bs[T][2];
      float go = a[3] + bs[T][3];
      float c = sigm(gf) * cst[T] + sigm(gi) * tanh_f(gg);
      cst[T] = c;
      h2[T] = sigm(go) * tanh_f(c);
    }
    // one aligned dword per lane; wave = 256B contiguous run.
    unsigned int hp = (unsigned int)f2bf(h2[0]) | ((unsigned int)f2bf(h2[1]) << 16);
    __hip_atomic_store(&Hw[(size_t)permt(t) * 16384 + st_dw], hp,
                       __ATOMIC_RELAXED, __HIP_MEMORY_SCOPE_AGENT);
    // r12's win: drain our store into the fabric BEFORE next step's loads.
    asm volatile("s_waitcnt vmcnt(0)" ::: "memory");
  }
}

// ---------------- k4: emissions GEMM (frag-order H) ----------------
__global__ __launch_bounds__(256) void k4_emis(
    const unsigned short* __restrict__ Hall, const unsigned short* __restrict__ fcw_bf,
    const float* __restrict__ fcb, float* __restrict__ em) {
  __shared__ short Fs[48 * 520];
  const int tid = threadIdx.x, l = tid & 63, wv = tid >> 6;
  const int t = blockIdx.x;                      // M-tile 64 = one timestep
  floatx4 acc[3];
  acc[0] = acc[1] = acc[2] = (floatx4){0.f, 0.f, 0.f, 0.f};
  for (int half = 0; half < 2; ++half) {
    __syncthreads();
#pragma unroll
    for (int i = 0; i < 24; ++i) {
      int e4 = (tid + i * 256) * 4;
      int n = e4 >> 9, k = e4 & 511;
      *(short4v*)(Fs + n * 520 + k) =
          *(const short4v*)(fcw_bf + (size_t)n * 1024 + half * 512 + k);
    }
    __syncthreads();
    const unsigned short* Hsrc = Hall + (size_t)half * 16777216 + (size_t)permt(t) * 32768
                                 + (size_t)wv * 8192 + l * 8;
#pragma unroll
    for (int ks = 0; ks < 16; ++ks) {
      short8 a = *(const short8*)(Hsrc + ks * 512);
#pragma unroll
      for (int nf = 0; nf < 3; ++nf) {
        short8 bfr = *(const short8*)(Fs + (nf * 16 + (l & 15)) * 520 + ks * 32 + (l >> 4) * 8);
        acc[nf] = __builtin_amdgcn_mfma_f32_16x16x32_bf16(a, bfr, acc[nf], 0, 0, 0);
      }
    }
  }
#pragma unroll
  for (int nf = 0; nf < 3; ++nf) {
    int n = nf * 16 + (l & 15);
    float bv = fcb[n];
#pragma unroll
    for (int r = 0; r < 4; ++r) {
      int m = wv * 16 + (l >> 4) * 4 + r;        // batch
      em[((size_t)t * 64 + m) * 48 + n] = acc[nf][r] + bv;
    }
  }
}

// ---------------- k5: CRF numerator ----------------
__global__ void k5_num(const float* __restrict__ em, const int* __restrict__ tags,
                       const float* __restrict__ start, const float* __restrict__ endt,
                       const float* __restrict__ trans, float* __restrict__ num) {
  const int b = blockIdx.x, tid = threadIdx.x;
  float s = 0.f;
  for (int t = 1 + tid; t < 512; t += 256) {
    int tg = tags[b * 512 + t], tp = tags[b * 512 + t - 1];
    s += em[(size_t)(t * 64 + b) * 48 + tg] + trans[tp * 48 + tg];
  }
  if (tid == 0) {
    int t0 = tags[b * 512];
    s += start[t0] + em[(size_t)b * 48 + t0] + endt[tags[b * 512 + 511]];
  }
  __shared__ float red[256];
  red[tid] = s;
  __syncthreads();
  for (int o = 128; o > 0; o >>= 1) {
    if (tid < o) red[tid] += red[tid + o];
    __syncthreads();
  }
  if (tid == 0) num[b] = red[0];
}

// ---------------- k6: CRF forward recursion (single wave, no barriers) ----------------
__global__ void k6_crf(const float* __restrict__ em, const float* __restrict__ trans,
                       const float* __restrict__ start, const float* __restrict__ endt,
                       float* __restrict__ logz) {
  const int b = blockIdx.x;
  const int j = threadIdx.x;   // 64 threads = ONE wave; lanes 48..63 inactive
  const bool act = j < 48;
  float Ecol[48];
#pragma unroll
  for (int i = 0; i < 48; ++i) Ecol[i] = act ? __expf(trans[i * 48 + j]) : 0.f;
  __shared__ float p[48];
  float alpha = act ? (start[j] + em[(size_t)b * 48 + j]) : -1e30f;
  for (int t = 1; t < 512; ++t) {
    float e_t = act ? em[(size_t)(t * 64 + b) * 48 + j] : 0.f;
    float m = alpha;
#pragma unroll
    for (int off = 32; off > 0; off >>= 1) m = fmaxf(m, __shfl_xor(m, off));
    if (act) p[j] = __expf(alpha - m);
    float ssum = 0.f;                       // single wave: LDS ops in-order, no barrier
#pragma unroll
    for (int i = 0; i < 48; ++i) ssum += p[i] * Ecol[i];
    alpha = act ? (m + __logf(ssum) + e_t) : -1e30f;
  }
  float v = act ? (alpha + endt[j]) : -1e30f;
  float m2 = v;
#pragma unroll
  for (int off = 32; off > 0; off >>= 1) m2 = fmaxf(m2, __shfl_xor(m2, off));
  float sz = act ? __expf(v - m2) : 0.f;
#pragma unroll
  for (int off = 32; off > 0; off >>= 1) sz += __shfl_xor(sz, off);
  if (j == 0) logz[b] = m2 + __logf(sz);
}

// ---------------- k7: final scalar ----------------
__global__ void k7_final(const float* __restrict__ num, const float* __restrict__ logz,
                         float* __restrict__ out) {
  int l = threadIdx.x;
  float v = num[l] - logz[l];
#pragma unroll
  for (int off = 32; off > 0; off >>= 1) v += __shfl_xor(v, off);
  if (l == 0) out[0] = -v * (1.0f / 64.0f);
}

// ---------------------------------------------------------------------------
extern "C" void kernel_launch(void* const* d_in, const int* in_sizes, int n_in,
                              void* d_out, int out_size, void* d_ws, size_t ws_size,
                              hipStream_t stream) {
  (void)in_sizes; (void)n_in; (void)out_size;
  if (ws_size < WS_NEED) return;

  const float* embedding = (const float*)d_in[0];
  const float* w_ih_f = (const float*)d_in[1];
  const float* w_hh_f = (const float*)d_in[2];
  const float* b_ih_f = (const float*)d_in[3];
  const float* b_hh_f = (const float*)d_in[4];
  const float* w_ih_b = (const float*)d_in[5];
  const float* w_hh_b = (const float*)d_in[6];
  const float* b_ih_b = (const float*)d_in[7];
  const float* b_hh_b = (const float*)d_in[8];
  const float* fc_w = (const float*)d_in[9];
  const float* fc_b = (const float*)d_in[10];
  const float* start_trans = (const float*)d_in[11];
  const float* end_trans = (const float*)d_in[12];
  const float* trans = (const float*)d_in[13];
  const int* x = (const int*)d_in[14];
  const int* tags = (const int*)d_in[15];

  char* ws = (char*)d_ws;
  unsigned short* Hall   = (unsigned short*)(ws + OFF_H);
  unsigned short* emb_bf = (unsigned short*)(ws + OFF_EMB);
  unsigned short* wfrag  = (unsigned short*)(ws + OFF_WIH);
  unsigned short* fcw_bf = (unsigned short*)(ws + OFF_FCW);
  float* bias  = (float*)(ws + OFF_BIAS);
  float* em    = (float*)(ws + OFF_EM);
  float* num   = (float*)(ws + OFF_NUM);
  float* logz  = (float*)(ws + OFF_LOGZ);

  k_init<<<16384, 256, 0, stream>>>((uint4*)Hall);
  k0_conv<<<8400, 256, 0, stream>>>(w_ih_f, w_ih_b, fc_w, b_ih_f, b_hh_f, b_ih_b, b_hh_b,
                                    wfrag, fcw_bf, bias);
  k1_embed<<<8192, 256, 0, stream>>>(embedding, x, emb_bf);
  k3_lstm<<<128, 256, 0, stream>>>(w_hh_f, w_hh_b, wfrag, emb_bf, bias, Hall);
  k4_emis<<<512, 256, 0, stream>>>(Hall, fcw_bf, fc_b, em);
  k5_num<<<64, 256, 0, stream>>>(em, tags, start_trans, end_trans, trans, num);
  k6_crf<<<64, 64, 0, stream>>>(em, trans, start_trans, end_trans, logz);
  k7_final<<<1, 64, 0, stream>>>(num, logz, (float*)d_out);
}